// Round 7
// baseline (622.639 us; speedup 1.0000x reference)
//
#include <hip/hip_runtime.h>
#include <hip/hip_bf16.h>
#include <stdint.h>

typedef unsigned int uint32;
typedef __attribute__((ext_vector_type(8))) short short8;   // 8 bf16 = 4 VGPRs
typedef __attribute__((ext_vector_type(4))) float float4v;  // MFMA C/D

#define FEAT 128
#define NGRAPH 64
#define SBLK 256     // scan blocks
#define STHR 256     // scan threads/block
#define SSEG 2       // elements per thread (256*256*2 = 131072 >= N)

// ---------- bf16 helpers ----------
__device__ __forceinline__ float bf2f_lo(uint32 v) {
    union { uint32 i; float f; } u; u.i = v << 16; return u.f;
}
__device__ __forceinline__ float bf2f_hi(uint32 v) {
    union { uint32 i; float f; } u; u.i = v & 0xffff0000u; return u.f;
}
__device__ __forceinline__ unsigned short f2bf(float f) {
    uint32 u = __builtin_bit_cast(uint32, f);
    uint32 r = (u + 0x7fffu + ((u >> 16) & 1u)) >> 16;      // RNE
    return (unsigned short)r;
}
__device__ __forceinline__ uint32 f2bf2(float lo, float hi) {
    return (uint32)f2bf(lo) | ((uint32)f2bf(hi) << 16);
}

// ---------- graph preprocessing ----------
__global__ void k_deg(const int* __restrict__ dst, int* __restrict__ counts, int E) {
    int e = blockIdx.x * blockDim.x + threadIdx.x;
    if (e < E) atomicAdd(&counts[dst[e]], 1);
}

__global__ void k_dinv(const int* __restrict__ counts, float* __restrict__ dinv, int N) {
    int i = blockIdx.x * blockDim.x + threadIdx.x;
    if (i < N) dinv[i] = rsqrtf((float)counts[i] + 1.0f);   // deg = in-deg + self loop
}

// ---- multi-block exclusive scan ----
__global__ void k_scan_a(const int* __restrict__ counts, int* __restrict__ tbase,
                         int* __restrict__ bsum, int N) {
    __shared__ int sc[STHR];
    int t = threadIdx.x, b = blockIdx.x;
    int g = b * STHR + t;
    int lo = g * SSEG;
    int s = 0;
#pragma unroll
    for (int j = 0; j < SSEG; j++) {
        int i = lo + j;
        if (i < N) s += counts[i];
    }
    sc[t] = s;
    __syncthreads();
    for (int off = 1; off < STHR; off <<= 1) {
        int v = (t >= off) ? sc[t - off] : 0;
        __syncthreads();
        sc[t] += v;
        __syncthreads();
    }
    tbase[g] = sc[t] - s;
    if (t == STHR - 1) bsum[b] = sc[t];
}

__global__ void k_scan_b(const int* __restrict__ bsum, int* __restrict__ bbase,
                         int* __restrict__ rowp, int N) {
    __shared__ int sc[SBLK];
    int t = threadIdx.x;
    int s = bsum[t];
    sc[t] = s;
    __syncthreads();
    for (int off = 1; off < SBLK; off <<= 1) {
        int v = (t >= off) ? sc[t - off] : 0;
        __syncthreads();
        sc[t] += v;
        __syncthreads();
    }
    bbase[t] = sc[t] - s;
    if (t == SBLK - 1) rowp[N] = sc[t];
}

__global__ void k_scan_c(const int* __restrict__ counts, const int* __restrict__ tbase,
                         const int* __restrict__ bbase, int* __restrict__ rowp,
                         int* __restrict__ cursor, int N) {
    int t = threadIdx.x, b = blockIdx.x;
    int g = b * STHR + t;
    int base = bbase[b] + tbase[g];
    int lo = g * SSEG;
#pragma unroll
    for (int j = 0; j < SSEG; j++) {
        int i = lo + j;
        if (i < N) { rowp[i] = base; cursor[i] = base; base += counts[i]; }
    }
}

// ---------- CSR fill: ONE scattered 4B store per edge (cw eliminated algebraically;
// GEMM epilogue pre-scales rows by dinv so agg is an unweighted sum) ----------
__global__ void k_fill(const int* __restrict__ src, const int* __restrict__ dst,
                       int* __restrict__ cursor, int* __restrict__ csrc, int E) {
    int e = blockIdx.x * blockDim.x + threadIdx.x;
    if (e >= E) return;
    int s = src[e], d = dst[e];
    int pos = atomicAdd(&cursor[d], 1);
    csrc[pos] = s;
}

// ---------- cast x f32 -> bf16 (packed) ----------
__global__ void k_cast(const float* __restrict__ X, uint32* __restrict__ Xb, long n2) {
    long i = (long)blockIdx.x * blockDim.x + threadIdx.x;
    long stride = (long)gridDim.x * blockDim.x;
    for (; i < n2; i += stride) {
        float2 v = *(const float2*)(X + 2 * i);
        Xb[i] = f2bf2(v.x, v.y);
    }
}

// ---------- pre-swizzle W into MFMA B-fragment order, bf16 ----
__global__ void k_wswz(const float* __restrict__ W, unsigned short* __restrict__ out) {
    int e = blockIdx.x * blockDim.x + threadIdx.x;          // 2048 entries
    if (e >= 2048) return;
    int kt = e >> 9, ct = (e >> 6) & 7, lane = e & 63;
    int krow = kt * 32 + (lane >> 4) * 8;
    int col = ct * 16 + (lane & 15);
#pragma unroll
    for (int j = 0; j < 8; j++)
        out[e * 8 + j] = f2bf(W[(krow + j) * FEAT + col]);
}

// ---------- MFMA GEMM: Hb[row] = dinv[row] * (X[row] @ W)  (bf16 out) ----------
__global__ void k_gemm(const uint32* __restrict__ Xb,
                       const unsigned short* __restrict__ Wswz,
                       const float* __restrict__ dinv,
                       unsigned short* __restrict__ Hb, int N) {
    __shared__ unsigned short Wl[FEAT * FEAT];              // 32 KB
    {
        const uint4* Wg = (const uint4*)Wswz;
        uint4* Ws = (uint4*)Wl;
        for (int i = threadIdx.x; i < 2048; i += 256) Ws[i] = Wg[i];
    }
    __syncthreads();

    int wave = threadIdx.x >> 6, lane = threadIdx.x & 63;
    int r0 = (blockIdx.x * 4 + wave) * 16;
    if (r0 >= N) return;
    int m = lane & 15, q = lane >> 4;

    int arow = r0 + m; if (arow >= N) arow = N - 1;
    const short8* Arow = (const short8*)((const unsigned short*)Xb + (long)arow * FEAT);
    short8 a0 = Arow[q + 0];
    short8 a1 = Arow[4 + q];
    short8 a2 = Arow[8 + q];
    short8 a3 = Arow[12 + q];

    const short8* Bl = (const short8*)Wl;
    float4v acc[8];
#pragma unroll
    for (int ct = 0; ct < 8; ct++) acc[ct] = (float4v){0.f, 0.f, 0.f, 0.f};

#pragma unroll
    for (int ct = 0; ct < 8; ct++) {
        acc[ct] = __builtin_amdgcn_mfma_f32_16x16x32_bf16(a0, Bl[(0 * 8 + ct) * 64 + lane], acc[ct], 0, 0, 0);
        acc[ct] = __builtin_amdgcn_mfma_f32_16x16x32_bf16(a1, Bl[(1 * 8 + ct) * 64 + lane], acc[ct], 0, 0, 0);
        acc[ct] = __builtin_amdgcn_mfma_f32_16x16x32_bf16(a2, Bl[(2 * 8 + ct) * 64 + lane], acc[ct], 0, 0, 0);
        acc[ct] = __builtin_amdgcn_mfma_f32_16x16x32_bf16(a3, Bl[(3 * 8 + ct) * 64 + lane], acc[ct], 0, 0, 0);
    }

    // C/D layout: col = lane&15, row = q*4 + reg ; scale rows by dinv
    float ds[4];
#pragma unroll
    for (int reg = 0; reg < 4; reg++) {
        int row = r0 + q * 4 + reg;
        ds[reg] = (row < N) ? dinv[row] : 0.f;
    }
#pragma unroll
    for (int ct = 0; ct < 8; ct++) {
#pragma unroll
        for (int reg = 0; reg < 4; reg++) {
            int row = r0 + q * 4 + reg;
            if (row < N) Hb[(long)row * FEAT + ct * 16 + m] = f2bf(acc[ct][reg] * ds[reg]);
        }
    }
}

// ---------- aggregation: OUT[i] = dinv_i * (sum_e Hb'[src_e] + Hb'[i]) + b ----------
// Hb' rows are pre-scaled by dinv at GEMM epilogue → hot loop is pure adds.
__global__ void k_agg(const uint32* __restrict__ Hb,
                      const int* __restrict__ rowp, const int* __restrict__ csrc,
                      const float* __restrict__ dinv, const float* __restrict__ bias,
                      uint32* __restrict__ OUTb, int N, int relu) {
    int wave = threadIdx.x >> 6, lane = threadIdx.x & 63;
    int i = blockIdx.x * 4 + wave;
    if (i >= N) return;
    float di = dinv[i];
    uint32 hv = Hb[(long)i * 64 + lane];
    float ax = bf2f_lo(hv), ay = bf2f_hi(hv);   // self term (already dinv-scaled)
    int e0 = rowp[i], e1 = rowp[i + 1];
    int e = e0;
    for (; e + 8 <= e1; e += 8) {
        int   s[8];
        uint32 h[8];
#pragma unroll
        for (int j = 0; j < 8; j++) s[j] = csrc[e + j];
#pragma unroll
        for (int j = 0; j < 8; j++) h[j] = Hb[(long)s[j] * 64 + lane];
#pragma unroll
        for (int j = 0; j < 8; j++) {
            ax += bf2f_lo(h[j]);
            ay += bf2f_hi(h[j]);
        }
    }
    {   // remainder (<8 edges), index-batched
        int   s[8];
        uint32 h[8];
        int r = e1 - e;
#pragma unroll
        for (int j = 0; j < 8; j++)
            if (j < r) s[j] = csrc[e + j];
#pragma unroll
        for (int j = 0; j < 8; j++)
            if (j < r) h[j] = Hb[(long)s[j] * 64 + lane];
#pragma unroll
        for (int j = 0; j < 8; j++)
            if (j < r) { ax += bf2f_lo(h[j]); ay += bf2f_hi(h[j]); }
    }
    ax = ax * di + bias[2 * lane];
    ay = ay * di + bias[2 * lane + 1];
    if (relu) { ax = fmaxf(ax, 0.f); ay = fmaxf(ay, 0.f); }
    OUTb[(long)i * 64 + lane] = f2bf2(ax, ay);
}

// ---------- pooling (batch sorted) ----------
__global__ void k_pool(const uint32* __restrict__ Gb, const int* __restrict__ batch,
                       float* __restrict__ pool, int* __restrict__ cntg, int N) {
    int t = threadIdx.x;                     // 64 threads: feat pair t
    int nb = gridDim.x;
    int chunk = (N + nb - 1) / nb;
    int lo = blockIdx.x * chunk, hi = min(lo + chunk, N);
    if (lo >= hi) return;
    float ax = 0.f, ay = 0.f;
    int cnt = 0;
    int cg = batch[lo];
    for (int i = lo; i < hi; i++) {
        int g = batch[i];
        if (g != cg) {
            atomicAdd(&pool[cg * FEAT + 2 * t], ax);
            atomicAdd(&pool[cg * FEAT + 2 * t + 1], ay);
            if (t == 0) atomicAdd(&cntg[cg], cnt);
            ax = ay = 0.f; cnt = 0; cg = g;
        }
        uint32 v = Gb[(long)i * 64 + t];
        ax += bf2f_lo(v); ay += bf2f_hi(v);
        cnt++;
    }
    atomicAdd(&pool[cg * FEAT + 2 * t], ax);
    atomicAdd(&pool[cg * FEAT + 2 * t + 1], ay);
    if (t == 0) atomicAdd(&cntg[cg], cnt);
}

// ---------- head ----------
__global__ void k_final(const float* __restrict__ pool, const int* __restrict__ cntg,
                        const float* __restrict__ Wlin, const float* __restrict__ blin,
                        float* __restrict__ out) {
    __shared__ float es[FEAT];
    int g = blockIdx.x, t = threadIdx.x;
    float c = (float)max(cntg[g], 1);
    float e = pool[g * FEAT + t] / c;
    es[t] = e;
    out[NGRAPH * 10 + g * FEAT + t] = e;
    __syncthreads();
    if (t < 10) {
        float a = blin[t];
        for (int k = 0; k < FEAT; k++)
            a += es[k] * Wlin[k * 10 + t];
        out[g * 10 + t] = a;
    }
}

// ---------------------------------------------------------------
extern "C" void kernel_launch(void* const* d_in, const int* in_sizes, int n_in,
                              void* d_out, int out_size, void* d_ws, size_t ws_size,
                              hipStream_t stream) {
    const float* x    = (const float*)d_in[0];
    const int*   ei   = (const int*)d_in[1];
    const int*   batch= (const int*)d_in[2];
    const float* W1   = (const float*)d_in[3];
    const float* b1   = (const float*)d_in[4];
    const float* W2   = (const float*)d_in[5];
    const float* b2   = (const float*)d_in[6];
    const float* W3   = (const float*)d_in[7];
    const float* b3   = (const float*)d_in[8];
    const float* Wlin = (const float*)d_in[9];
    const float* blin = (const float*)d_in[10];

    const int N = in_sizes[2];
    const int E = in_sizes[1] / 2;
    const int* src = ei;
    const int* dst = ei + E;

    // ---- workspace carve ----
    char* w = (char*)d_ws;
    auto take = [&](size_t bytes) {
        char* p = w;
        w += (bytes + 255) & ~(size_t)255;
        return p;
    };
    int*    counts = (int*)   take((size_t)N * 4);
    float*  dinv   = (float*) take((size_t)N * 4);
    int*    rowp   = (int*)   take((size_t)(N + 1) * 4);
    int*    cursor = (int*)   take((size_t)N * 4);
    int*    csrc   = (int*)   take((size_t)E * 4);
    uint32* xb     = (uint32*)take((size_t)N * FEAT * 2);
    uint32* hbuf   = (uint32*)take((size_t)N * FEAT * 2);
    uint32* gbuf   = (uint32*)take((size_t)N * FEAT * 2);
    unsigned short* w1s = (unsigned short*)take(FEAT * FEAT * 2);
    unsigned short* w2s = (unsigned short*)take(FEAT * FEAT * 2);
    unsigned short* w3s = (unsigned short*)take(FEAT * FEAT * 2);
    float*  pool   = (float*) take((size_t)NGRAPH * FEAT * 4);
    int*    cntg   = (int*)   take((size_t)NGRAPH * 4);
    int*    tbase  = (int*)   take((size_t)SBLK * STHR * 4);
    int*    bsum   = (int*)   take((size_t)SBLK * 4);
    int*    bbase  = (int*)   take((size_t)SBLK * 4);
    (void)ws_size; (void)n_in; (void)out_size;

    const int be = (E + 255) / 256;
    const int bn = (N + 255) / 256;

    hipMemsetAsync(counts, 0, (size_t)N * 4, stream);
    hipMemsetAsync(pool,   0, (size_t)NGRAPH * FEAT * 4, stream);
    hipMemsetAsync(cntg,   0, (size_t)NGRAPH * 4, stream);

    // graph preprocessing (CSR by dst); multi-block scan
    k_deg   <<<be, 256, 0, stream>>>(dst, counts, E);
    k_dinv  <<<bn, 256, 0, stream>>>(counts, dinv, N);
    k_scan_a<<<SBLK, STHR, 0, stream>>>(counts, tbase, bsum, N);
    k_scan_b<<<1, SBLK, 0, stream>>>(bsum, bbase, rowp, N);
    k_scan_c<<<SBLK, STHR, 0, stream>>>(counts, tbase, bbase, rowp, cursor, N);
    k_fill  <<<be, 256, 0, stream>>>(src, dst, cursor, csrc, E);

    // casts / weight swizzles
    k_cast<<<2048, 256, 0, stream>>>(x, xb, (long)N * FEAT / 2);
    k_wswz<<<8, 256, 0, stream>>>(W1, w1s);
    k_wswz<<<8, 256, 0, stream>>>(W2, w2s);
    k_wswz<<<8, 256, 0, stream>>>(W3, w3s);

    const int gemm_blocks = (N + 63) / 64;
    const int agg_blocks  = (N + 3) / 4;

    // layer 1
    k_gemm<<<gemm_blocks, 256, 0, stream>>>(xb, w1s, dinv, (unsigned short*)hbuf, N);
    k_agg <<<agg_blocks, 256, 0, stream>>>(hbuf, rowp, csrc, dinv, b1, gbuf, N, 1);
    // layer 2
    k_gemm<<<gemm_blocks, 256, 0, stream>>>(gbuf, w2s, dinv, (unsigned short*)hbuf, N);
    k_agg <<<agg_blocks, 256, 0, stream>>>(hbuf, rowp, csrc, dinv, b2, gbuf, N, 1);
    // layer 3
    k_gemm<<<gemm_blocks, 256, 0, stream>>>(gbuf, w3s, dinv, (unsigned short*)hbuf, N);
    k_agg <<<agg_blocks, 256, 0, stream>>>(hbuf, rowp, csrc, dinv, b3, gbuf, N, 0);

    // pooling + head
    k_pool <<<1024, 64, 0, stream>>>(gbuf, batch, pool, cntg, N);
    k_final<<<NGRAPH, 128, 0, stream>>>(pool, cntg, Wlin, blin, (float*)d_out);
}

// Round 8
// 491.479 us; speedup vs baseline: 1.2669x; 1.2669x over previous
//
#include <hip/hip_runtime.h>
#include <hip/hip_bf16.h>
#include <stdint.h>

typedef unsigned int uint32;
typedef __attribute__((ext_vector_type(8))) short short8;   // 8 bf16 = 4 VGPRs
typedef __attribute__((ext_vector_type(4))) float float4v;  // MFMA C/D

#define FEAT 128
#define NGRAPH 64
#define SBLK 256     // scan blocks
#define STHR 256     // scan threads/block
#define SSEG 2       // elements per thread (256*256*2 = 131072 >= N)
#define GB   256     // binning blocks
#define NBK  512     // bucket slots (>= ceil(N/256))

// ---------- bf16 helpers ----------
__device__ __forceinline__ float bf2f_lo(uint32 v) {
    union { uint32 i; float f; } u; u.i = v << 16; return u.f;
}
__device__ __forceinline__ float bf2f_hi(uint32 v) {
    union { uint32 i; float f; } u; u.i = v & 0xffff0000u; return u.f;
}
__device__ __forceinline__ unsigned short f2bf(float f) {
    uint32 u = __builtin_bit_cast(uint32, f);
    uint32 r = (u + 0x7fffu + ((u >> 16) & 1u)) >> 16;      // RNE
    return (unsigned short)r;
}
__device__ __forceinline__ uint32 f2bf2(float lo, float hi) {
    return (uint32)f2bf(lo) | ((uint32)f2bf(hi) << 16);
}

// ================= preprocessing: atomic-free coarse counting sort =================
// R7 lesson: 1.6M random global atomics (k_deg + k_fill) are latency-bound (~230 us)
// regardless of store bytes. Replace with LDS-histogram binning (bucket = dst>>8).

// phase 1: per-block LDS histogram of coarse buckets -> bhist[blk][NBK] (coalesced)
__global__ void k_bhist(const int* __restrict__ dst, int* __restrict__ bhist, int E) {
    __shared__ int h[NBK];
    int t = threadIdx.x, blk = blockIdx.x;
    for (int b = t; b < NBK; b += 256) h[b] = 0;
    __syncthreads();
    int chunk = (E + GB - 1) / GB;
    int lo = blk * chunk, hi = min(lo + chunk, E);
    for (int e = lo + t; e < hi; e += 256)
        atomicAdd(&h[dst[e] >> 8], 1);
    __syncthreads();
    for (int b = t; b < NBK; b += 256) bhist[blk * NBK + b] = h[b];
}

// phase 2 (1 block, 512 thr): column prefix over blocks + bucket scan -> offsets
// bhist[blk][b] becomes exclusive prefix within bucket; bbase[b] = bucket start.
__global__ void k_boffs(int* __restrict__ bhist, int* __restrict__ bbase) {
    __shared__ int sc[NBK];
    int t = threadIdx.x;                     // one thread per bucket
    int tot = 0;
    for (int blk = 0; blk < GB; blk++) {
        int v = bhist[blk * NBK + t];
        bhist[blk * NBK + t] = tot;
        tot += v;
    }
    sc[t] = tot;
    __syncthreads();
    for (int off = 1; off < NBK; off <<= 1) {
        int v = (t >= off) ? sc[t - off] : 0;
        __syncthreads();
        sc[t] += v;
        __syncthreads();
    }
    bbase[t] = sc[t] - tot;                  // exclusive
    if (t == NBK - 1) bbase[NBK] = sc[t];
}

// phase 3: scatter edges into bucket-sorted ebuf, packed (src<<8)|(dst&255).
// LDS cursors from precomputed offsets -> zero global atomics; per-(blk,bucket)
// output runs contiguous -> near-1x write amplification.
__global__ void k_bscat(const int* __restrict__ src, const int* __restrict__ dst,
                        const int* __restrict__ bhist, const int* __restrict__ bbase,
                        uint32* __restrict__ ebuf, int E) {
    __shared__ int cur[NBK];
    int t = threadIdx.x, blk = blockIdx.x;
    for (int b = t; b < NBK; b += 256) cur[b] = bbase[b] + bhist[blk * NBK + b];
    __syncthreads();
    int chunk = (E + GB - 1) / GB;
    int lo = blk * chunk, hi = min(lo + chunk, E);
    for (int e = lo + t; e < hi; e += 256) {
        int d = dst[e], s = src[e];
        int b = d >> 8;
        int p = atomicAdd(&cur[b], 1);       // LDS atomic (fast)
        ebuf[p] = ((uint32)s << 8) | (uint32)(d & 255);
    }
}

// phase 4: per-bucket LDS histogram -> counts[node]  (replaces k_deg's 1.6M atomics)
__global__ void k_count2(const uint32* __restrict__ ebuf, const int* __restrict__ bbase,
                         int* __restrict__ counts, int N) {
    __shared__ int h[256];
    int t = threadIdx.x, b = blockIdx.x;
    h[t] = 0;
    __syncthreads();
    int e0 = bbase[b], e1 = bbase[b + 1];
    for (int e = e0 + t; e < e1; e += 256)
        atomicAdd(&h[ebuf[e] & 255u], 1);
    __syncthreads();
    int node = b * 256 + t;
    if (node < N) counts[node] = h[t];
}

// phase 5: per-bucket CSR fill via LDS cursors; stores land in the bucket's
// ~16KB L2-resident slice of csrc  (replaces k_fill's 1.6M atomics)
__global__ void k_fill2(const uint32* __restrict__ ebuf, const int* __restrict__ bbase,
                        const int* __restrict__ rowp, int* __restrict__ csrc, int N) {
    __shared__ int cur[256];
    int t = threadIdx.x, b = blockIdx.x;
    int node = b * 256 + t;
    cur[t] = (node < N) ? rowp[node] : 0;
    __syncthreads();
    int e0 = bbase[b], e1 = bbase[b + 1];
    for (int e = e0 + t; e < e1; e += 256) {
        uint32 v = ebuf[e];
        int p = atomicAdd(&cur[v & 255u], 1);    // LDS atomic
        csrc[p] = (int)(v >> 8);
    }
}

// ---------- dinv ----------
__global__ void k_dinv(const int* __restrict__ counts, float* __restrict__ dinv, int N) {
    int i = blockIdx.x * blockDim.x + threadIdx.x;
    if (i < N) dinv[i] = rsqrtf((float)counts[i] + 1.0f);   // deg = in-deg + self loop
}

// ---- multi-block exclusive scan of counts -> rowp ----
__global__ void k_scan_a(const int* __restrict__ counts, int* __restrict__ tbase,
                         int* __restrict__ bsum, int N) {
    __shared__ int sc[STHR];
    int t = threadIdx.x, b = blockIdx.x;
    int g = b * STHR + t;
    int lo = g * SSEG;
    int s = 0;
#pragma unroll
    for (int j = 0; j < SSEG; j++) {
        int i = lo + j;
        if (i < N) s += counts[i];
    }
    sc[t] = s;
    __syncthreads();
    for (int off = 1; off < STHR; off <<= 1) {
        int v = (t >= off) ? sc[t - off] : 0;
        __syncthreads();
        sc[t] += v;
        __syncthreads();
    }
    tbase[g] = sc[t] - s;
    if (t == STHR - 1) bsum[b] = sc[t];
}

__global__ void k_scan_b(const int* __restrict__ bsum, int* __restrict__ bbase2,
                         int* __restrict__ rowp, int N) {
    __shared__ int sc[SBLK];
    int t = threadIdx.x;
    int s = bsum[t];
    sc[t] = s;
    __syncthreads();
    for (int off = 1; off < SBLK; off <<= 1) {
        int v = (t >= off) ? sc[t - off] : 0;
        __syncthreads();
        sc[t] += v;
        __syncthreads();
    }
    bbase2[t] = sc[t] - s;
    if (t == SBLK - 1) rowp[N] = sc[t];
}

__global__ void k_scan_c(const int* __restrict__ counts, const int* __restrict__ tbase,
                         const int* __restrict__ bbase2, int* __restrict__ rowp, int N) {
    int t = threadIdx.x, b = blockIdx.x;
    int g = b * STHR + t;
    int base = bbase2[b] + tbase[g];
    int lo = g * SSEG;
#pragma unroll
    for (int j = 0; j < SSEG; j++) {
        int i = lo + j;
        if (i < N) { rowp[i] = base; base += counts[i]; }
    }
}

// ---------- cast x f32 -> bf16 (packed) ----------
__global__ void k_cast(const float* __restrict__ X, uint32* __restrict__ Xb, long n2) {
    long i = (long)blockIdx.x * blockDim.x + threadIdx.x;
    long stride = (long)gridDim.x * blockDim.x;
    for (; i < n2; i += stride) {
        float2 v = *(const float2*)(X + 2 * i);
        Xb[i] = f2bf2(v.x, v.y);
    }
}

// ---------- pre-swizzle W into MFMA B-fragment order, bf16 ----
__global__ void k_wswz(const float* __restrict__ W, unsigned short* __restrict__ out) {
    int e = blockIdx.x * blockDim.x + threadIdx.x;          // 2048 entries
    if (e >= 2048) return;
    int kt = e >> 9, ct = (e >> 6) & 7, lane = e & 63;
    int krow = kt * 32 + (lane >> 4) * 8;
    int col = ct * 16 + (lane & 15);
#pragma unroll
    for (int j = 0; j < 8; j++)
        out[e * 8 + j] = f2bf(W[(krow + j) * FEAT + col]);
}

// ---------- MFMA GEMM: Hb[row] = dinv[row] * (X[row] @ W)  (bf16 out) ----------
__global__ void k_gemm(const uint32* __restrict__ Xb,
                       const unsigned short* __restrict__ Wswz,
                       const float* __restrict__ dinv,
                       unsigned short* __restrict__ Hb, int N) {
    __shared__ unsigned short Wl[FEAT * FEAT];              // 32 KB
    {
        const uint4* Wg = (const uint4*)Wswz;
        uint4* Ws = (uint4*)Wl;
        for (int i = threadIdx.x; i < 2048; i += 256) Ws[i] = Wg[i];
    }
    __syncthreads();

    int wave = threadIdx.x >> 6, lane = threadIdx.x & 63;
    int r0 = (blockIdx.x * 4 + wave) * 16;
    if (r0 >= N) return;
    int m = lane & 15, q = lane >> 4;

    int arow = r0 + m; if (arow >= N) arow = N - 1;
    const short8* Arow = (const short8*)((const unsigned short*)Xb + (long)arow * FEAT);
    short8 a0 = Arow[q + 0];
    short8 a1 = Arow[4 + q];
    short8 a2 = Arow[8 + q];
    short8 a3 = Arow[12 + q];

    const short8* Bl = (const short8*)Wl;
    float4v acc[8];
#pragma unroll
    for (int ct = 0; ct < 8; ct++) acc[ct] = (float4v){0.f, 0.f, 0.f, 0.f};

#pragma unroll
    for (int ct = 0; ct < 8; ct++) {
        acc[ct] = __builtin_amdgcn_mfma_f32_16x16x32_bf16(a0, Bl[(0 * 8 + ct) * 64 + lane], acc[ct], 0, 0, 0);
        acc[ct] = __builtin_amdgcn_mfma_f32_16x16x32_bf16(a1, Bl[(1 * 8 + ct) * 64 + lane], acc[ct], 0, 0, 0);
        acc[ct] = __builtin_amdgcn_mfma_f32_16x16x32_bf16(a2, Bl[(2 * 8 + ct) * 64 + lane], acc[ct], 0, 0, 0);
        acc[ct] = __builtin_amdgcn_mfma_f32_16x16x32_bf16(a3, Bl[(3 * 8 + ct) * 64 + lane], acc[ct], 0, 0, 0);
    }

    // C/D layout: col = lane&15, row = q*4 + reg ; scale rows by dinv
    float ds[4];
#pragma unroll
    for (int reg = 0; reg < 4; reg++) {
        int row = r0 + q * 4 + reg;
        ds[reg] = (row < N) ? dinv[row] : 0.f;
    }
#pragma unroll
    for (int ct = 0; ct < 8; ct++) {
#pragma unroll
        for (int reg = 0; reg < 4; reg++) {
            int row = r0 + q * 4 + reg;
            if (row < N) Hb[(long)row * FEAT + ct * 16 + m] = f2bf(acc[ct][reg] * ds[reg]);
        }
    }
}

// ---------- aggregation: OUT[i] = dinv_i * (sum_e Hb'[src_e] + Hb'[i]) + b ----------
__global__ void k_agg(const uint32* __restrict__ Hb,
                      const int* __restrict__ rowp, const int* __restrict__ csrc,
                      const float* __restrict__ dinv, const float* __restrict__ bias,
                      uint32* __restrict__ OUTb, int N, int relu) {
    int wave = threadIdx.x >> 6, lane = threadIdx.x & 63;
    int i = blockIdx.x * 4 + wave;
    if (i >= N) return;
    float di = dinv[i];
    uint32 hv = Hb[(long)i * 64 + lane];
    float ax = bf2f_lo(hv), ay = bf2f_hi(hv);   // self term (already dinv-scaled)
    int e0 = rowp[i], e1 = rowp[i + 1];
    int e = e0;
    for (; e + 8 <= e1; e += 8) {
        int   s[8];
        uint32 h[8];
#pragma unroll
        for (int j = 0; j < 8; j++) s[j] = csrc[e + j];
#pragma unroll
        for (int j = 0; j < 8; j++) h[j] = Hb[(long)s[j] * 64 + lane];
#pragma unroll
        for (int j = 0; j < 8; j++) {
            ax += bf2f_lo(h[j]);
            ay += bf2f_hi(h[j]);
        }
    }
    {   // remainder (<8 edges), index-batched
        int   s[8];
        uint32 h[8];
        int r = e1 - e;
#pragma unroll
        for (int j = 0; j < 8; j++)
            if (j < r) s[j] = csrc[e + j];
#pragma unroll
        for (int j = 0; j < 8; j++)
            if (j < r) h[j] = Hb[(long)s[j] * 64 + lane];
#pragma unroll
        for (int j = 0; j < 8; j++)
            if (j < r) { ax += bf2f_lo(h[j]); ay += bf2f_hi(h[j]); }
    }
    ax = ax * di + bias[2 * lane];
    ay = ay * di + bias[2 * lane + 1];
    if (relu) { ax = fmaxf(ax, 0.f); ay = fmaxf(ay, 0.f); }
    OUTb[(long)i * 64 + lane] = f2bf2(ax, ay);
}

// ---------- pooling (batch sorted) ----------
__global__ void k_pool(const uint32* __restrict__ Gb, const int* __restrict__ batch,
                       float* __restrict__ pool, int* __restrict__ cntg, int N) {
    int t = threadIdx.x;                     // 64 threads: feat pair t
    int nb = gridDim.x;
    int chunk = (N + nb - 1) / nb;
    int lo = blockIdx.x * chunk, hi = min(lo + chunk, N);
    if (lo >= hi) return;
    float ax = 0.f, ay = 0.f;
    int cnt = 0;
    int cg = batch[lo];
    for (int i = lo; i < hi; i++) {
        int g = batch[i];
        if (g != cg) {
            atomicAdd(&pool[cg * FEAT + 2 * t], ax);
            atomicAdd(&pool[cg * FEAT + 2 * t + 1], ay);
            if (t == 0) atomicAdd(&cntg[cg], cnt);
            ax = ay = 0.f; cnt = 0; cg = g;
        }
        uint32 v = Gb[(long)i * 64 + t];
        ax += bf2f_lo(v); ay += bf2f_hi(v);
        cnt++;
    }
    atomicAdd(&pool[cg * FEAT + 2 * t], ax);
    atomicAdd(&pool[cg * FEAT + 2 * t + 1], ay);
    if (t == 0) atomicAdd(&cntg[cg], cnt);
}

// ---------- head ----------
__global__ void k_final(const float* __restrict__ pool, const int* __restrict__ cntg,
                        const float* __restrict__ Wlin, const float* __restrict__ blin,
                        float* __restrict__ out) {
    __shared__ float es[FEAT];
    int g = blockIdx.x, t = threadIdx.x;
    float c = (float)max(cntg[g], 1);
    float e = pool[g * FEAT + t] / c;
    es[t] = e;
    out[NGRAPH * 10 + g * FEAT + t] = e;
    __syncthreads();
    if (t < 10) {
        float a = blin[t];
        for (int k = 0; k < FEAT; k++)
            a += es[k] * Wlin[k * 10 + t];
        out[g * 10 + t] = a;
    }
}

// ---------------------------------------------------------------
extern "C" void kernel_launch(void* const* d_in, const int* in_sizes, int n_in,
                              void* d_out, int out_size, void* d_ws, size_t ws_size,
                              hipStream_t stream) {
    const float* x    = (const float*)d_in[0];
    const int*   ei   = (const int*)d_in[1];
    const int*   batch= (const int*)d_in[2];
    const float* W1   = (const float*)d_in[3];
    const float* b1   = (const float*)d_in[4];
    const float* W2   = (const float*)d_in[5];
    const float* b2   = (const float*)d_in[6];
    const float* W3   = (const float*)d_in[7];
    const float* b3   = (const float*)d_in[8];
    const float* Wlin = (const float*)d_in[9];
    const float* blin = (const float*)d_in[10];

    const int N = in_sizes[2];
    const int E = in_sizes[1] / 2;
    const int* src = ei;
    const int* dst = ei + E;
    const int NB = (N + 255) >> 8;           // coarse buckets actually used (<= NBK)

    // ---- workspace carve ----
    char* w = (char*)d_ws;
    auto take = [&](size_t bytes) {
        char* p = w;
        w += (bytes + 255) & ~(size_t)255;
        return p;
    };
    int*    counts = (int*)   take((size_t)N * 4);
    float*  dinv   = (float*) take((size_t)N * 4);
    int*    rowp   = (int*)   take((size_t)(N + 1) * 4);
    int*    csrc   = (int*)   take((size_t)E * 4);
    uint32* ebuf   = (uint32*)take((size_t)E * 4);
    int*    bhist  = (int*)   take((size_t)GB * NBK * 4);
    int*    bbase  = (int*)   take((size_t)(NBK + 1) * 4);
    uint32* xb     = (uint32*)take((size_t)N * FEAT * 2);
    uint32* hbuf   = (uint32*)take((size_t)N * FEAT * 2);
    uint32* gbuf   = (uint32*)take((size_t)N * FEAT * 2);
    unsigned short* w1s = (unsigned short*)take(FEAT * FEAT * 2);
    unsigned short* w2s = (unsigned short*)take(FEAT * FEAT * 2);
    unsigned short* w3s = (unsigned short*)take(FEAT * FEAT * 2);
    float*  pool   = (float*) take((size_t)NGRAPH * FEAT * 4);
    int*    cntg   = (int*)   take((size_t)NGRAPH * 4);
    int*    tbase  = (int*)   take((size_t)SBLK * STHR * 4);
    int*    bsum   = (int*)   take((size_t)SBLK * 4);
    int*    bbase2 = (int*)   take((size_t)SBLK * 4);
    (void)ws_size; (void)n_in; (void)out_size;

    const int bn = (N + 255) / 256;

    hipMemsetAsync(pool, 0, (size_t)NGRAPH * FEAT * 4, stream);
    hipMemsetAsync(cntg, 0, (size_t)NGRAPH * 4, stream);

    // --- atomic-free CSR build ---
    k_bhist <<<GB, 256, 0, stream>>>(dst, bhist, E);
    k_boffs <<<1, NBK, 0, stream>>>(bhist, bbase);
    k_bscat <<<GB, 256, 0, stream>>>(src, dst, bhist, bbase, ebuf, E);
    k_count2<<<NB, 256, 0, stream>>>(ebuf, bbase, counts, N);
    k_dinv  <<<bn, 256, 0, stream>>>(counts, dinv, N);
    k_scan_a<<<SBLK, STHR, 0, stream>>>(counts, tbase, bsum, N);
    k_scan_b<<<1, SBLK, 0, stream>>>(bsum, bbase2, rowp, N);
    k_scan_c<<<SBLK, STHR, 0, stream>>>(counts, tbase, bbase2, rowp, N);
    k_fill2 <<<NB, 256, 0, stream>>>(ebuf, bbase, rowp, csrc, N);

    // casts / weight swizzles
    k_cast<<<2048, 256, 0, stream>>>(x, xb, (long)N * FEAT / 2);
    k_wswz<<<8, 256, 0, stream>>>(W1, w1s);
    k_wswz<<<8, 256, 0, stream>>>(W2, w2s);
    k_wswz<<<8, 256, 0, stream>>>(W3, w3s);

    const int gemm_blocks = (N + 63) / 64;
    const int agg_blocks  = (N + 3) / 4;

    // layer 1
    k_gemm<<<gemm_blocks, 256, 0, stream>>>(xb, w1s, dinv, (unsigned short*)hbuf, N);
    k_agg <<<agg_blocks, 256, 0, stream>>>(hbuf, rowp, csrc, dinv, b1, gbuf, N, 1);
    // layer 2
    k_gemm<<<gemm_blocks, 256, 0, stream>>>(gbuf, w2s, dinv, (unsigned short*)hbuf, N);
    k_agg <<<agg_blocks, 256, 0, stream>>>(hbuf, rowp, csrc, dinv, b2, gbuf, N, 1);
    // layer 3
    k_gemm<<<gemm_blocks, 256, 0, stream>>>(gbuf, w3s, dinv, (unsigned short*)hbuf, N);
    k_agg <<<agg_blocks, 256, 0, stream>>>(hbuf, rowp, csrc, dinv, b3, gbuf, N, 0);

    // pooling + head
    k_pool <<<1024, 64, 0, stream>>>(gbuf, batch, pool, cntg, N);
    k_final<<<NGRAPH, 128, 0, stream>>>(pool, cntg, Wlin, blin, (float*)d_out);
}

// Round 9
// 464.682 us; speedup vs baseline: 1.3399x; 1.0577x over previous
//
#include <hip/hip_runtime.h>
#include <hip/hip_bf16.h>
#include <stdint.h>

typedef unsigned int uint32;
typedef __attribute__((ext_vector_type(8))) short short8;   // 8 bf16 = 4 VGPRs
typedef __attribute__((ext_vector_type(4))) float float4v;  // MFMA C/D

#define FEAT 128
#define NGRAPH 64
#define SBLK 256     // scan blocks
#define STHR 256     // scan threads/block
#define SSEG 2       // elements per thread (256*256*2 = 131072 >= N)
#define GB   256     // binning blocks
#define NBK  512     // bucket slots (>= ceil(N/256))

// ---------- bf16 helpers ----------
__device__ __forceinline__ float bf2f_lo(uint32 v) {
    union { uint32 i; float f; } u; u.i = v << 16; return u.f;
}
__device__ __forceinline__ float bf2f_hi(uint32 v) {
    union { uint32 i; float f; } u; u.i = v & 0xffff0000u; return u.f;
}
__device__ __forceinline__ unsigned short f2bf(float f) {
    uint32 u = __builtin_bit_cast(uint32, f);
    uint32 r = (u + 0x7fffu + ((u >> 16) & 1u)) >> 16;      // RNE
    return (unsigned short)r;
}
__device__ __forceinline__ uint32 f2bf2(float lo, float hi) {
    return (uint32)f2bf(lo) | ((uint32)f2bf(hi) << 16);
}

// ================= preprocessing: atomic-free coarse counting sort =================
__global__ void k_bhist(const int* __restrict__ dst, int* __restrict__ bhist, int E) {
    __shared__ int h[NBK];
    int t = threadIdx.x, blk = blockIdx.x;
    for (int b = t; b < NBK; b += 256) h[b] = 0;
    __syncthreads();
    int chunk = (E + GB - 1) / GB;
    int lo = blk * chunk, hi = min(lo + chunk, E);
    for (int e = lo + t; e < hi; e += 256)
        atomicAdd(&h[dst[e] >> 8], 1);
    __syncthreads();
    for (int b = t; b < NBK; b += 256) bhist[blk * NBK + b] = h[b];
}

__global__ void k_boffs(int* __restrict__ bhist, int* __restrict__ bbase) {
    __shared__ int sc[NBK];
    int t = threadIdx.x;                     // one thread per bucket
    int tot = 0;
    for (int blk = 0; blk < GB; blk++) {
        int v = bhist[blk * NBK + t];
        bhist[blk * NBK + t] = tot;
        tot += v;
    }
    sc[t] = tot;
    __syncthreads();
    for (int off = 1; off < NBK; off <<= 1) {
        int v = (t >= off) ? sc[t - off] : 0;
        __syncthreads();
        sc[t] += v;
        __syncthreads();
    }
    bbase[t] = sc[t] - tot;                  // exclusive
    if (t == NBK - 1) bbase[NBK] = sc[t];
}

__global__ void k_bscat(const int* __restrict__ src, const int* __restrict__ dst,
                        const int* __restrict__ bhist, const int* __restrict__ bbase,
                        uint32* __restrict__ ebuf, int E) {
    __shared__ int cur[NBK];
    int t = threadIdx.x, blk = blockIdx.x;
    for (int b = t; b < NBK; b += 256) cur[b] = bbase[b] + bhist[blk * NBK + b];
    __syncthreads();
    int chunk = (E + GB - 1) / GB;
    int lo = blk * chunk, hi = min(lo + chunk, E);
    for (int e = lo + t; e < hi; e += 256) {
        int d = dst[e], s = src[e];
        int b = d >> 8;
        int p = atomicAdd(&cur[b], 1);       // LDS atomic
        ebuf[p] = ((uint32)s << 8) | (uint32)(d & 255);
    }
}

// per-bucket LDS histogram -> counts[node] + dinv[node] (k_dinv fused)
__global__ void k_count2(const uint32* __restrict__ ebuf, const int* __restrict__ bbase,
                         int* __restrict__ counts, float* __restrict__ dinv, int N) {
    __shared__ int h[256];
    int t = threadIdx.x, b = blockIdx.x;
    h[t] = 0;
    __syncthreads();
    int e0 = bbase[b], e1 = bbase[b + 1];
    for (int e = e0 + t; e < e1; e += 256)
        atomicAdd(&h[ebuf[e] & 255u], 1);
    __syncthreads();
    int node = b * 256 + t;
    if (node < N) {
        counts[node] = h[t];
        dinv[node] = rsqrtf((float)h[t] + 1.0f);     // deg = in-deg + self loop
    }
}

__global__ void k_fill2(const uint32* __restrict__ ebuf, const int* __restrict__ bbase,
                        const int* __restrict__ rowp, int* __restrict__ csrc, int N) {
    __shared__ int cur[256];
    int t = threadIdx.x, b = blockIdx.x;
    int node = b * 256 + t;
    cur[t] = (node < N) ? rowp[node] : 0;
    __syncthreads();
    int e0 = bbase[b], e1 = bbase[b + 1];
    for (int e = e0 + t; e < e1; e += 256) {
        uint32 v = ebuf[e];
        int p = atomicAdd(&cur[v & 255u], 1);    // LDS atomic
        csrc[p] = (int)(v >> 8);
    }
}

// ---- multi-block exclusive scan of counts -> rowp ----
__global__ void k_scan_a(const int* __restrict__ counts, int* __restrict__ tbase,
                         int* __restrict__ bsum, int N) {
    __shared__ int sc[STHR];
    int t = threadIdx.x, b = blockIdx.x;
    int g = b * STHR + t;
    int lo = g * SSEG;
    int s = 0;
#pragma unroll
    for (int j = 0; j < SSEG; j++) {
        int i = lo + j;
        if (i < N) s += counts[i];
    }
    sc[t] = s;
    __syncthreads();
    for (int off = 1; off < STHR; off <<= 1) {
        int v = (t >= off) ? sc[t - off] : 0;
        __syncthreads();
        sc[t] += v;
        __syncthreads();
    }
    tbase[g] = sc[t] - s;
    if (t == STHR - 1) bsum[b] = sc[t];
}

__global__ void k_scan_b(const int* __restrict__ bsum, int* __restrict__ bbase2,
                         int* __restrict__ rowp, int N) {
    __shared__ int sc[SBLK];
    int t = threadIdx.x;
    int s = bsum[t];
    sc[t] = s;
    __syncthreads();
    for (int off = 1; off < SBLK; off <<= 1) {
        int v = (t >= off) ? sc[t - off] : 0;
        __syncthreads();
        sc[t] += v;
        __syncthreads();
    }
    bbase2[t] = sc[t] - s;
    if (t == SBLK - 1) rowp[N] = sc[t];
}

__global__ void k_scan_c(const int* __restrict__ counts, const int* __restrict__ tbase,
                         const int* __restrict__ bbase2, int* __restrict__ rowp, int N) {
    int t = threadIdx.x, b = blockIdx.x;
    int g = b * STHR + t;
    int base = bbase2[b] + tbase[g];
    int lo = g * SSEG;
#pragma unroll
    for (int j = 0; j < SSEG; j++) {
        int i = lo + j;
        if (i < N) { rowp[i] = base; base += counts[i]; }
    }
}

// ---------- pre-swizzle W1/W2/W3 into MFMA B-fragment order, one launch ----------
__global__ void k_wswz3(const float* __restrict__ W1, const float* __restrict__ W2,
                        const float* __restrict__ W3, unsigned short* __restrict__ o1,
                        unsigned short* __restrict__ o2, unsigned short* __restrict__ o3) {
    int wid = blockIdx.x >> 3;               // 8 blocks per weight
    const float* W = (wid == 0) ? W1 : (wid == 1) ? W2 : W3;
    unsigned short* out = (wid == 0) ? o1 : (wid == 1) ? o2 : o3;
    int e = (blockIdx.x & 7) * 256 + threadIdx.x;  // 2048 entries
    int kt = e >> 9, ct = (e >> 6) & 7, lane = e & 63;
    int krow = kt * 32 + (lane >> 4) * 8;
    int col = ct * 16 + (lane & 15);
#pragma unroll
    for (int j = 0; j < 8; j++)
        out[e * 8 + j] = f2bf(W[(krow + j) * FEAT + col]);
}

// ---------- MFMA GEMM: Hb[row] = dinv[row] * (X[row] @ W)  (bf16 out) ----------
// F32IN: read f32 rows (layer 1; inputs are bf16-valued so in-register cast is lossless)
template <bool F32IN>
__global__ void k_gemm(const void* __restrict__ Xp,
                       const unsigned short* __restrict__ Wswz,
                       const float* __restrict__ dinv,
                       unsigned short* __restrict__ Hb, int N) {
    __shared__ unsigned short Wl[FEAT * FEAT];              // 32 KB
    {
        const uint4* Wg = (const uint4*)Wswz;
        uint4* Ws = (uint4*)Wl;
        for (int i = threadIdx.x; i < 2048; i += 256) Ws[i] = Wg[i];
    }
    __syncthreads();

    int wave = threadIdx.x >> 6, lane = threadIdx.x & 63;
    int r0 = (blockIdx.x * 4 + wave) * 16;
    if (r0 >= N) return;
    int m = lane & 15, q = lane >> 4;

    int arow = r0 + m; if (arow >= N) arow = N - 1;
    short8 a[4];
    if (F32IN) {
        const float* Ar = (const float*)Xp + (long)arow * FEAT;
#pragma unroll
        for (int kt = 0; kt < 4; kt++) {
            float4 u = *(const float4*)(Ar + kt * 32 + q * 8);
            float4 v = *(const float4*)(Ar + kt * 32 + q * 8 + 4);
            short8 t;
            t[0] = (short)f2bf(u.x); t[1] = (short)f2bf(u.y);
            t[2] = (short)f2bf(u.z); t[3] = (short)f2bf(u.w);
            t[4] = (short)f2bf(v.x); t[5] = (short)f2bf(v.y);
            t[6] = (short)f2bf(v.z); t[7] = (short)f2bf(v.w);
            a[kt] = t;
        }
    } else {
        const short8* Ar = (const short8*)((const unsigned short*)Xp + (long)arow * FEAT);
#pragma unroll
        for (int kt = 0; kt < 4; kt++) a[kt] = Ar[kt * 4 + q];
    }

    const short8* Bl = (const short8*)Wl;
    float4v acc[8];
#pragma unroll
    for (int ct = 0; ct < 8; ct++) acc[ct] = (float4v){0.f, 0.f, 0.f, 0.f};

#pragma unroll
    for (int ct = 0; ct < 8; ct++) {
        acc[ct] = __builtin_amdgcn_mfma_f32_16x16x32_bf16(a[0], Bl[(0 * 8 + ct) * 64 + lane], acc[ct], 0, 0, 0);
        acc[ct] = __builtin_amdgcn_mfma_f32_16x16x32_bf16(a[1], Bl[(1 * 8 + ct) * 64 + lane], acc[ct], 0, 0, 0);
        acc[ct] = __builtin_amdgcn_mfma_f32_16x16x32_bf16(a[2], Bl[(2 * 8 + ct) * 64 + lane], acc[ct], 0, 0, 0);
        acc[ct] = __builtin_amdgcn_mfma_f32_16x16x32_bf16(a[3], Bl[(3 * 8 + ct) * 64 + lane], acc[ct], 0, 0, 0);
    }

    // C/D layout: col = lane&15, row = q*4 + reg ; scale rows by dinv
    float ds[4];
#pragma unroll
    for (int reg = 0; reg < 4; reg++) {
        int row = r0 + q * 4 + reg;
        ds[reg] = (row < N) ? dinv[row] : 0.f;
    }
#pragma unroll
    for (int ct = 0; ct < 8; ct++) {
#pragma unroll
        for (int reg = 0; reg < 4; reg++) {
            int row = r0 + q * 4 + reg;
            if (row < N) Hb[(long)row * FEAT + ct * 16 + m] = f2bf(acc[ct][reg] * ds[reg]);
        }
    }
}

// ---------- aggregation: OUT[i] = dinv_i * (sum_e Hb'[src_e] + Hb'[i]) + b ----------
// Half-wave scheme: lanes 0-31 / 32-63 process different edges of the SAME node,
// each half reading the 256B row as uint2 (8B x 32 lanes) -> one VMEM instruction
// covers 2 rows (512B). Epilogue combines halves via shfl_xor(32).
__global__ void k_agg(const uint32* __restrict__ Hb,
                      const int* __restrict__ rowp, const int* __restrict__ csrc,
                      const float* __restrict__ dinv, const float* __restrict__ bias,
                      uint32* __restrict__ OUTb, int N, int relu) {
    int wave = threadIdx.x >> 6, lane = threadIdx.x & 63;
    int i = blockIdx.x * 4 + wave;
    if (i >= N) return;
    int f = lane & 31, half = lane >> 5;
    const uint2* H2 = (const uint2*)Hb;
    float a0 = 0.f, a1 = 0.f, a2 = 0.f, a3 = 0.f;
    int e0 = rowp[i], e1 = rowp[i + 1];
    int e = e0;
    for (; e + 16 <= e1; e += 16) {          // 16 edges/iter (8 per half)
        int  s[8];
        uint2 h[8];
#pragma unroll
        for (int j = 0; j < 8; j++) s[j] = csrc[e + 2 * j + half];
#pragma unroll
        for (int j = 0; j < 8; j++) h[j] = H2[(long)s[j] * 32 + f];
#pragma unroll
        for (int j = 0; j < 8; j++) {
            a0 += bf2f_lo(h[j].x); a1 += bf2f_hi(h[j].x);
            a2 += bf2f_lo(h[j].y); a3 += bf2f_hi(h[j].y);
        }
    }
    {   // remainder (<16 edges), predicated
        int r = e1 - e;
        int  s[8];
        uint2 h[8];
#pragma unroll
        for (int j = 0; j < 8; j++) {
            int idx = 2 * j + half;
            if (idx < r) s[j] = csrc[e + idx];
        }
#pragma unroll
        for (int j = 0; j < 8; j++)
            if (2 * j + half < r) h[j] = H2[(long)s[j] * 32 + f];
#pragma unroll
        for (int j = 0; j < 8; j++)
            if (2 * j + half < r) {
                a0 += bf2f_lo(h[j].x); a1 += bf2f_hi(h[j].x);
                a2 += bf2f_lo(h[j].y); a3 += bf2f_hi(h[j].y);
            }
    }
    // combine halves
    a0 += __shfl_xor(a0, 32);
    a1 += __shfl_xor(a1, 32);
    a2 += __shfl_xor(a2, 32);
    a3 += __shfl_xor(a3, 32);
    if (half == 0) {
        uint2 hv = H2[(long)i * 32 + f];     // self term (already dinv-scaled)
        a0 += bf2f_lo(hv.x); a1 += bf2f_hi(hv.x);
        a2 += bf2f_lo(hv.y); a3 += bf2f_hi(hv.y);
        float di = dinv[i];
        float4 bb = ((const float4*)bias)[f];
        a0 = a0 * di + bb.x; a1 = a1 * di + bb.y;
        a2 = a2 * di + bb.z; a3 = a3 * di + bb.w;
        if (relu) {
            a0 = fmaxf(a0, 0.f); a1 = fmaxf(a1, 0.f);
            a2 = fmaxf(a2, 0.f); a3 = fmaxf(a3, 0.f);
        }
        uint2 o;
        o.x = f2bf2(a0, a1);
        o.y = f2bf2(a2, a3);
        ((uint2*)OUTb)[(long)i * 32 + f] = o;
    }
}

// ---------- pooling (batch sorted) ----------
__global__ void k_pool(const uint32* __restrict__ Gb, const int* __restrict__ batch,
                       float* __restrict__ pool, int* __restrict__ cntg, int N) {
    int t = threadIdx.x;                     // 64 threads: feat pair t
    int nb = gridDim.x;
    int chunk = (N + nb - 1) / nb;
    int lo = blockIdx.x * chunk, hi = min(lo + chunk, N);
    if (lo >= hi) return;
    float ax = 0.f, ay = 0.f;
    int cnt = 0;
    int cg = batch[lo];
    for (int i = lo; i < hi; i++) {
        int g = batch[i];
        if (g != cg) {
            atomicAdd(&pool[cg * FEAT + 2 * t], ax);
            atomicAdd(&pool[cg * FEAT + 2 * t + 1], ay);
            if (t == 0) atomicAdd(&cntg[cg], cnt);
            ax = ay = 0.f; cnt = 0; cg = g;
        }
        uint32 v = Gb[(long)i * 64 + t];
        ax += bf2f_lo(v); ay += bf2f_hi(v);
        cnt++;
    }
    atomicAdd(&pool[cg * FEAT + 2 * t], ax);
    atomicAdd(&pool[cg * FEAT + 2 * t + 1], ay);
    if (t == 0) atomicAdd(&cntg[cg], cnt);
}

// ---------- head ----------
__global__ void k_final(const float* __restrict__ pool, const int* __restrict__ cntg,
                        const float* __restrict__ Wlin, const float* __restrict__ blin,
                        float* __restrict__ out) {
    __shared__ float es[FEAT];
    int g = blockIdx.x, t = threadIdx.x;
    float c = (float)max(cntg[g], 1);
    float e = pool[g * FEAT + t] / c;
    es[t] = e;
    out[NGRAPH * 10 + g * FEAT + t] = e;
    __syncthreads();
    if (t < 10) {
        float a = blin[t];
        for (int k = 0; k < FEAT; k++)
            a += es[k] * Wlin[k * 10 + t];
        out[g * 10 + t] = a;
    }
}

// ---------------------------------------------------------------
extern "C" void kernel_launch(void* const* d_in, const int* in_sizes, int n_in,
                              void* d_out, int out_size, void* d_ws, size_t ws_size,
                              hipStream_t stream) {
    const float* x    = (const float*)d_in[0];
    const int*   ei   = (const int*)d_in[1];
    const int*   batch= (const int*)d_in[2];
    const float* W1   = (const float*)d_in[3];
    const float* b1   = (const float*)d_in[4];
    const float* W2   = (const float*)d_in[5];
    const float* b2   = (const float*)d_in[6];
    const float* W3   = (const float*)d_in[7];
    const float* b3   = (const float*)d_in[8];
    const float* Wlin = (const float*)d_in[9];
    const float* blin = (const float*)d_in[10];

    const int N = in_sizes[2];
    const int E = in_sizes[1] / 2;
    const int* src = ei;
    const int* dst = ei + E;
    const int NB = (N + 255) >> 8;           // coarse buckets actually used (<= NBK)

    // ---- workspace carve ----
    char* w = (char*)d_ws;
    auto take = [&](size_t bytes) {
        char* p = w;
        w += (bytes + 255) & ~(size_t)255;
        return p;
    };
    int*    counts = (int*)   take((size_t)N * 4);
    float*  dinv   = (float*) take((size_t)N * 4);
    int*    rowp   = (int*)   take((size_t)(N + 1) * 4);
    int*    csrc   = (int*)   take((size_t)E * 4);
    uint32* ebuf   = (uint32*)take((size_t)E * 4);
    int*    bhist  = (int*)   take((size_t)GB * NBK * 4);
    int*    bbase  = (int*)   take((size_t)(NBK + 1) * 4);
    uint32* hbuf   = (uint32*)take((size_t)N * FEAT * 2);
    uint32* gbuf   = (uint32*)take((size_t)N * FEAT * 2);
    unsigned short* w1s = (unsigned short*)take(FEAT * FEAT * 2);
    unsigned short* w2s = (unsigned short*)take(FEAT * FEAT * 2);
    unsigned short* w3s = (unsigned short*)take(FEAT * FEAT * 2);
    float*  pool   = (float*) take((size_t)NGRAPH * FEAT * 4);
    int*    cntg   = (int*)   take((size_t)NGRAPH * 4);
    int*    tbase  = (int*)   take((size_t)SBLK * STHR * 4);
    int*    bsum   = (int*)   take((size_t)SBLK * 4);
    int*    bbase2 = (int*)   take((size_t)SBLK * 4);
    (void)ws_size; (void)n_in; (void)out_size;

    hipMemsetAsync(pool, 0, (size_t)NGRAPH * FEAT * 4, stream);
    hipMemsetAsync(cntg, 0, (size_t)NGRAPH * 4, stream);

    // --- atomic-free CSR build ---
    k_bhist <<<GB, 256, 0, stream>>>(dst, bhist, E);
    k_boffs <<<1, NBK, 0, stream>>>(bhist, bbase);
    k_bscat <<<GB, 256, 0, stream>>>(src, dst, bhist, bbase, ebuf, E);
    k_count2<<<NB, 256, 0, stream>>>(ebuf, bbase, counts, dinv, N);
    k_scan_a<<<SBLK, STHR, 0, stream>>>(counts, tbase, bsum, N);
    k_scan_b<<<1, SBLK, 0, stream>>>(bsum, bbase2, rowp, N);
    k_scan_c<<<SBLK, STHR, 0, stream>>>(counts, tbase, bbase2, rowp, N);
    k_fill2 <<<NB, 256, 0, stream>>>(ebuf, bbase, rowp, csrc, N);

    // weight swizzles (one launch for all 3)
    k_wswz3<<<24, 256, 0, stream>>>(W1, W2, W3, w1s, w2s, w3s);

    const int gemm_blocks = (N + 63) / 64;
    const int agg_blocks  = (N + 3) / 4;

    // layer 1 (reads f32 x directly; in-register bf16 cast is lossless)
    k_gemm<true> <<<gemm_blocks, 256, 0, stream>>>(x, w1s, dinv, (unsigned short*)hbuf, N);
    k_agg <<<agg_blocks, 256, 0, stream>>>(hbuf, rowp, csrc, dinv, b1, gbuf, N, 1);
    // layer 2
    k_gemm<false><<<gemm_blocks, 256, 0, stream>>>(gbuf, w2s, dinv, (unsigned short*)hbuf, N);
    k_agg <<<agg_blocks, 256, 0, stream>>>(hbuf, rowp, csrc, dinv, b2, gbuf, N, 1);
    // layer 3
    k_gemm<false><<<gemm_blocks, 256, 0, stream>>>(gbuf, w3s, dinv, (unsigned short*)hbuf, N);
    k_agg <<<agg_blocks, 256, 0, stream>>>(hbuf, rowp, csrc, dinv, b3, gbuf, N, 0);

    // pooling + head
    k_pool <<<1024, 64, 0, stream>>>(gbuf, batch, pool, cntg, N);
    k_final<<<NGRAPH, 128, 0, stream>>>(pool, cntg, Wlin, blin, (float*)d_out);
}